// Round 2
// baseline (117.547 us; speedup 1.0000x reference)
//
#include <hip/hip_runtime.h>
#include <math.h>

// SchurDecompositionLinear collapses algebraically:
//   apply_P right-multiplies by Q = H0*H1*...*H{n-1} (orthogonal, each Hi
//   symmetric involutory), so W = (T*Q)*(I*Q)^T = T*Q*Q^T = T exactly.
// T is block-diagonal 2x2: gamma_k * [[c,-s],[s,c]].
// out = x @ T is an elementwise pairwise rotation — pure HBM-bound stream
// (64 MiB read + 64 MiB write -> ~20.4 us floor at 6.3 TB/s).

#define NCOLS 256
#define F4_PER_ROW (NCOLS / 4)  // 64

// Grid-stride with stride % 64 == 0: each thread's column (and thus its
// rotation coefficients) is loop-invariant -> sincos once, no LDS, no barrier.
__global__ __launch_bounds__(256) void schur_rot_kernel(
    const float4* __restrict__ x4,
    const float* __restrict__ theta,
    const float* __restrict__ gamma,
    float4* __restrict__ out4,
    int total4)
{
    int tid = blockIdx.x * blockDim.x + threadIdx.x;
    int stride = gridDim.x * blockDim.x;      // multiple of 64 (block=256)

    int col4 = tid & (F4_PER_ROW - 1);        // float4 column, loop-invariant
    int k0 = 2 * col4;                        // pair index for (.x,.y)

    float s0, c0, s1, c1;
    sincosf(theta[k0],     &s0, &c0);
    sincosf(theta[k0 + 1], &s1, &c1);
    float g0 = gamma[k0], g1 = gamma[k0 + 1];
    c0 *= g0; s0 *= g0;
    c1 *= g1; s1 *= g1;

    int idx = tid;
    // main loop: 4 independent float4 loads in flight per wave
    for (; idx + 3 * stride < total4; idx += 4 * stride) {
        float4 v0 = x4[idx];
        float4 v1 = x4[idx + stride];
        float4 v2 = x4[idx + 2 * stride];
        float4 v3 = x4[idx + 3 * stride];

        float4 o0, o1, o2, o3;
        o0.x = fmaf(c0, v0.x,  s0 * v0.y);
        o0.y = fmaf(c0, v0.y, -s0 * v0.x);
        o0.z = fmaf(c1, v0.z,  s1 * v0.w);
        o0.w = fmaf(c1, v0.w, -s1 * v0.z);
        o1.x = fmaf(c0, v1.x,  s0 * v1.y);
        o1.y = fmaf(c0, v1.y, -s0 * v1.x);
        o1.z = fmaf(c1, v1.z,  s1 * v1.w);
        o1.w = fmaf(c1, v1.w, -s1 * v1.z);
        o2.x = fmaf(c0, v2.x,  s0 * v2.y);
        o2.y = fmaf(c0, v2.y, -s0 * v2.x);
        o2.z = fmaf(c1, v2.z,  s1 * v2.w);
        o2.w = fmaf(c1, v2.w, -s1 * v2.z);
        o3.x = fmaf(c0, v3.x,  s0 * v3.y);
        o3.y = fmaf(c0, v3.y, -s0 * v3.x);
        o3.z = fmaf(c1, v3.z,  s1 * v3.w);
        o3.w = fmaf(c1, v3.w, -s1 * v3.z);

        out4[idx]              = o0;
        out4[idx + stride]     = o1;
        out4[idx + 2 * stride] = o2;
        out4[idx + 3 * stride] = o3;
    }
    // remainder
    for (; idx < total4; idx += stride) {
        float4 v = x4[idx];
        float4 o;
        o.x = fmaf(c0, v.x,  s0 * v.y);
        o.y = fmaf(c0, v.y, -s0 * v.x);
        o.z = fmaf(c1, v.z,  s1 * v.w);
        o.w = fmaf(c1, v.w, -s1 * v.z);
        out4[idx] = o;
    }
}

extern "C" void kernel_launch(void* const* d_in, const int* in_sizes, int n_in,
                              void* d_out, int out_size, void* d_ws, size_t ws_size,
                              hipStream_t stream) {
    const float* x     = (const float*)d_in[0];   // [rows, 256]
    // d_in[1] = U — unused: Householder product cancels exactly (Q*Q^T = I)
    const float* theta = (const float*)d_in[2];   // [128]
    const float* gamma = (const float*)d_in[3];   // [128]
    float* out = (float*)d_out;

    int total  = in_sizes[0];          // rows * 256
    int total4 = total / 4;            // float4 count

    int block = 256;
    int grid  = 2048;                  // 8 blocks/CU; 8 float4/thread at 65536 rows
    int maxgrid = (total4 + block - 1) / block;
    if (grid > maxgrid) grid = maxgrid;

    schur_rot_kernel<<<grid, block, 0, stream>>>(
        (const float4*)x, theta, gamma, (float4*)out, total4);
}